// Round 4
// baseline (1495.292 us; speedup 1.0000x reference)
//
#include <hip/hip_runtime.h>
#include <cstdint>
#include <cstddef>

#define H_DIM 4096
#define DFF_DIM 16384
#define NROWS 4096  // B*S = 2*2048

typedef unsigned short bf16_t;
typedef __attribute__((ext_vector_type(8))) short bf16x8;
typedef __attribute__((ext_vector_type(4))) float f32x4;
typedef __attribute__((ext_vector_type(4))) unsigned short u16x4;

static __device__ __forceinline__ bf16_t f2bf(float f) {
  union { float f; unsigned int i; } v; v.f = f;
  unsigned int x = v.i;
  return (bf16_t)((x + 0x7fffu + ((x >> 16) & 1u)) >> 16);  // RNE
}

// global -> LDS direct async copy, 16B per lane (wave-uniform base + lane*16).
#define GLDS16(gp, lp)                                                    \
  __builtin_amdgcn_global_load_lds(                                       \
      (__attribute__((address_space(1))) void*)(gp),                      \
      (__attribute__((address_space(3))) void*)(lp), 16, 0, 0)

#define SB0 __builtin_amdgcn_sched_barrier(0)

// ---------------------------------------------------------------------------
// Kernel 1: ln_in = input + residual + bias; LN(ln_in, gamma, beta) -> bf16
// ---------------------------------------------------------------------------
__global__ __launch_bounds__(256) void fused_ln_kernel(
    const float* __restrict__ inp, const float* __restrict__ res,
    const float* __restrict__ bias, const float* __restrict__ gamma,
    const float* __restrict__ beta, bf16_t* __restrict__ out) {
  int row = blockIdx.x;
  int t = threadIdx.x;
  const float4* pin = (const float4*)(inp + (size_t)row * H_DIM);
  const float4* pre = (const float4*)(res + (size_t)row * H_DIM);
  const float4* pbi = (const float4*)bias;
  float4 xv[4];
  float s = 0.f, ss = 0.f;
#pragma unroll
  for (int i = 0; i < 4; ++i) {
    int idx = t + i * 256;
    float4 a = pin[idx];
    float4 b = pre[idx];
    float4 c = pbi[idx];
    float4 v;
    v.x = a.x + b.x + c.x;
    v.y = a.y + b.y + c.y;
    v.z = a.z + b.z + c.z;
    v.w = a.w + b.w + c.w;
    xv[i] = v;
    s += v.x + v.y + v.z + v.w;
    ss += v.x * v.x + v.y * v.y + v.z * v.z + v.w * v.w;
  }
#pragma unroll
  for (int off = 32; off > 0; off >>= 1) {
    s += __shfl_xor(s, off);
    ss += __shfl_xor(ss, off);
  }
  __shared__ float sred[8];
  int w = t >> 6, l = t & 63;
  if (l == 0) { sred[w] = s; sred[4 + w] = ss; }
  __syncthreads();
  s = sred[0] + sred[1] + sred[2] + sred[3];
  ss = sred[4] + sred[5] + sred[6] + sred[7];
  const float inv = 1.f / (float)H_DIM;
  float mean = s * inv;
  float var = ss * inv - mean * mean;
  float rstd = rsqrtf(var + 1e-5f);
  const float4* pg = (const float4*)gamma;
  const float4* pb = (const float4*)beta;
#pragma unroll
  for (int i = 0; i < 4; ++i) {
    int idx = t + i * 256;
    float4 g = pg[idx];
    float4 bb = pb[idx];
    float4 v = xv[i];
    u16x4 o;
    o.x = f2bf((v.x - mean) * rstd * g.x + bb.x);
    o.y = f2bf((v.y - mean) * rstd * g.y + bb.y);
    o.z = f2bf((v.z - mean) * rstd * g.z + bb.z);
    o.w = f2bf((v.w - mean) * rstd * g.w + bb.w);
    *(u16x4*)(out + (size_t)row * H_DIM + (size_t)idx * 4) = o;
  }
}

// ---------------------------------------------------------------------------
// Kernel 2: W fp32 [K,N] -> Wt bf16 [N,K] (transpose + convert).
// ---------------------------------------------------------------------------
__global__ __launch_bounds__(256) void transpose_cvt_kernel(
    const float* __restrict__ W, bf16_t* __restrict__ Wt, int K, int N) {
  __shared__ float tile[64][65];
  int nb = N >> 6;
  int bk = blockIdx.x / nb;
  int bn = blockIdx.x - bk * nb;
  int t = threadIdx.x;
  int r = t >> 4;
  int c4 = (t & 15) << 2;
#pragma unroll
  for (int p = 0; p < 4; ++p) {
    int row = r + p * 16;
    float4 v = *(const float4*)(W + (size_t)(bk * 64 + row) * N + bn * 64 + c4);
    tile[row][c4 + 0] = v.x;
    tile[row][c4 + 1] = v.y;
    tile[row][c4 + 2] = v.z;
    tile[row][c4 + 3] = v.w;
  }
  __syncthreads();
#pragma unroll
  for (int p = 0; p < 4; ++p) {
    int nn = r + p * 16;
    u16x4 o;
    o.x = f2bf(tile[c4 + 0][nn]);
    o.y = f2bf(tile[c4 + 1][nn]);
    o.z = f2bf(tile[c4 + 2][nn]);
    o.w = f2bf(tile[c4 + 3][nn]);
    *(u16x4*)(Wt + (size_t)(bn * 64 + nn) * K + bk * 64 + c4) = o;
  }
}

// ---------------------------------------------------------------------------
// Kernel 3: 256x256-tile bf16 GEMM (C = A[M,K] * Bt[N,K]^T), fp32 acc.
// 512 threads = 8 waves (2M x 4N), per-wave 128x64 out = acc[8][4] frags.
// 160 KB LDS: A triple-buffered (3 x 32KB), B double-buffered (2 x 32KB).
// Per K-tile (BK=64): 4 phases; stages at P1..P4 prefetch tile T+2; ONE
// vmcnt(8) wait per tile at P4 retiring exactly the previous tile's 4 stages
// (ages 4-7 phases, ~800-1400cy -> covers HBM latency). sched_barrier(0)
// pins stage/wait placement against codegen reordering.
// XOR slot swizzle on GLOBAL source + re-applied on ds_read (conflict-free).
// EPI 0: out_bf16 = gelu_tanh(C + eb1[n])
// EPI 1: out_f32  = C + eb1[n] + eb2[n] + add1[m,n] + add2[m,n]
// ---------------------------------------------------------------------------
#define PHASE_TAIL(MIBASE)                                                  \
  __builtin_amdgcn_s_barrier();                                             \
  asm volatile("s_waitcnt lgkmcnt(0)" ::: "memory");                        \
  __builtin_amdgcn_sched_barrier(0);                                        \
  __builtin_amdgcn_s_setprio(1);                                            \
  _Pragma("unroll") for (int ii = 0; ii < 4; ++ii)                          \
      _Pragma("unroll") for (int jj = 0; jj < 4; ++jj) acc[MIBASE + ii][jj] = \
      __builtin_amdgcn_mfma_f32_16x16x32_bf16(aF[ii], bF[jj],               \
                                              acc[MIBASE + ii][jj], 0, 0, 0); \
  __builtin_amdgcn_s_setprio(0);                                            \
  __builtin_amdgcn_s_barrier();

template <int EPI>
__global__ __launch_bounds__(512, 2) void gemm8p_kernel(
    const bf16_t* __restrict__ A, const bf16_t* __restrict__ Bt,
    int M, int N, int K,
    const float* __restrict__ eb1, const float* __restrict__ eb2,
    const float* __restrict__ add1, const float* __restrict__ add2,
    bf16_t* __restrict__ outb, float* __restrict__ outf) {
  __shared__ char lds[163840];  // A: 3 x 32KB @0, B: 2 x 32KB @98304

  const int t = threadIdx.x;
  const int l = t & 63;
  const int wid = t >> 6;
  const int wr = wid >> 2;  // 0..1
  const int wc = wid & 3;   // 0..3

  // Block -> tile: XCD chunk swizzle, then 2-wide tn bands, tm-major.
  int nwg = gridDim.x;
  int bid = blockIdx.x;
  int wg = (bid & 7) * (nwg >> 3) + (bid >> 3);
  int band = wg >> 5;
  int r5 = wg & 31;
  int tn = band * 2 + (r5 & 1);
  int tm = r5 >> 1;
  size_t m0 = (size_t)tm * 256, n0 = (size_t)tn * 256;

  f32x4 acc[8][4];
#pragma unroll
  for (int i = 0; i < 8; ++i)
#pragma unroll
    for (int j = 0; j < 4; ++j) acc[i][j] = {0.f, 0.f, 0.f, 0.f};

  // Staging: half-tile = 256 rows x 32 k (16KB) = 1024 chunks of 16B.
  // Thread t covers chunks t and t+512 (LDS linear). Source k-slot pre-XORed.
  const int c0 = t, c1 = t + 512;
  const int row0 = c0 >> 2, row1 = c1 >> 2;
  const int ks0 = (c0 & 3) ^ ((row0 >> 1) & 3);
  const int ks1 = (c1 & 3) ^ ((row1 >> 1) & 3);
  const bf16_t* pA0 = A + (m0 + row0) * (size_t)K + ks0 * 8;
  const bf16_t* pA1 = A + (m0 + row1) * (size_t)K + ks1 * 8;
  const bf16_t* pB0 = Bt + (n0 + row0) * (size_t)K + ks0 * 8;
  const bf16_t* pB1 = Bt + (n0 + row1) * (size_t)K + ks1 * 8;

  auto stageA = [&](int base, int h, int T) {
    GLDS16(pA0 + (size_t)T * 64 + h * 32, lds + base + h * 16384 + c0 * 16);
    GLDS16(pA1 + (size_t)T * 64 + h * 32, lds + base + h * 16384 + c1 * 16);
  };
  auto stageB = [&](int base, int h, int T) {
    GLDS16(pB0 + (size_t)T * 64 + h * 32, lds + base + h * 16384 + c0 * 16);
    GLDS16(pB1 + (size_t)T * 64 + h * 32, lds + base + h * 16384 + c1 * 16);
  };

  // ds_read offsets: lane reads row=(base+(l&15)), k-octet (l>>4); physical
  // slot = (l>>4) ^ ((row>>1)&3) = (l>>4) ^ ((l>>1)&3)  (bases are 16-aligned).
  const int slot = (((l >> 4) ^ ((l >> 1) & 3)) << 4);
  int aoffs[8], boffs[4];
#pragma unroll
  for (int mi = 0; mi < 8; ++mi)
    aoffs[mi] = (wr * 128 + mi * 16 + (l & 15)) * 64 + slot;
#pragma unroll
  for (int nj = 0; nj < 4; ++nj)
    boffs[nj] = (wc * 64 + nj * 16 + (l & 15)) * 64 + slot;

  auto rd8 = [&](int off) -> bf16x8 {
    return *(const bf16x8*)(const void*)(lds + off);
  };

  const int NT = K >> 6;  // K-tiles of 64

  // Prologue: tile0 -> A[0]/B[0], tile1 -> A[1]/B[1] (16 loads).
  // vmcnt(8) retires tile0's 8 loads (consumed from T=0.P1).
  stageA(0, 0, 0);
  stageB(98304, 0, 0);
  stageA(0, 1, 0);
  stageB(98304, 1, 0);
  stageA(32768, 0, 1);
  stageB(98304 + 32768, 0, 1);
  stageA(32768, 1, 1);
  stageB(98304 + 32768, 1, 1);
  SB0;
  asm volatile("s_waitcnt vmcnt(8)" ::: "memory");
  SB0;
  __builtin_amdgcn_s_barrier();

  int aC = 0, aS = 2;  // A read-buffer index, A stage-buffer index ((T+2)%3)
  for (int T = 0; T < NT; ++T) {
    const int bB = 98304 + (T & 1) * 32768;   // B buffer (parity of T == T+2)
    const int aCb = aC * 32768;
    const int aSb = aS * 32768;
    int Tg = T + 2;
    if (Tg >= NT) Tg = NT - 1;  // tail: dead prefetch (never consumed)
    bf16x8 aF[4], bF[4];
    // P1: kk0 — B nj0-3 + A mi0-3; stage A[T+2] H0
#pragma unroll
    for (int j = 0; j < 4; ++j) bF[j] = rd8(bB + boffs[j]);
#pragma unroll
    for (int i2 = 0; i2 < 4; ++i2) aF[i2] = rd8(aCb + aoffs[i2]);
    stageA(aSb, 0, Tg);
    SB0;
    PHASE_TAIL(0)
    // P2: kk0 — A mi4-7 (bF reused); stage B[T+2] H0
#pragma unroll
    for (int i2 = 0; i2 < 4; ++i2) aF[i2] = rd8(aCb + aoffs[4 + i2]);
    stageB(bB, 0, Tg);
    SB0;
    PHASE_TAIL(4)
    // P3: kk1 — B + A mi0-3; stage A[T+2] H1
#pragma unroll
    for (int j = 0; j < 4; ++j) bF[j] = rd8(bB + boffs[j] + 16384);
#pragma unroll
    for (int i2 = 0; i2 < 4; ++i2) aF[i2] = rd8(aCb + aoffs[i2] + 16384);
    stageA(aSb, 1, Tg);
    SB0;
    PHASE_TAIL(0)
    // P4: kk1 — A mi4-7; stage B[T+2] H1; ONE wait/tile: vmcnt(8) retires
    // exactly the previous tile's 4 stages (tile T+1 data, ages 4-7 phases).
#pragma unroll
    for (int i2 = 0; i2 < 4; ++i2) aF[i2] = rd8(aCb + aoffs[4 + i2] + 16384);
    stageB(bB, 1, Tg);
    SB0;
    asm volatile("s_waitcnt vmcnt(8)" ::: "memory");
    SB0;
    PHASE_TAIL(4)
    // rotate A buffers: next read buf = aC+1 (mod 3); next stage buf = old aC
    aS = aC;
    aC = (aC == 2) ? 0 : aC + 1;
  }
  asm volatile("s_waitcnt vmcnt(0)" ::: "memory");

  // Epilogue. C/D: col = lane&15, row = (lane>>4)*4 + reg.
  int mb = (int)m0 + wr * 128;
  int nb2 = (int)n0 + wc * 64;
  int lr = (l >> 4) * 4;
  int lc = l & 15;
#pragma unroll
  for (int mi = 0; mi < 8; ++mi) {
#pragma unroll
    for (int i2 = 0; i2 < 4; ++i2) {
      int rrow = mb + mi * 16 + lr + i2;
      size_t base = (size_t)rrow * N;
#pragma unroll
      for (int nj = 0; nj < 4; ++nj) {
        int col = nb2 + nj * 16 + lc;
        float v = acc[mi][nj][i2];
        if (EPI == 0) {
          float x = v + eb1[col];
          float u = 0.7978845608028654f * (x + 0.044715f * x * x * x);
          float th = 1.f - 2.f / (__expf(2.f * u) + 1.f);  // tanh(u)
          outb[base + col] = f2bf(0.5f * x * (1.f + th));
        } else {
          outf[base + col] =
              v + eb1[col] + eb2[col] + add1[base + col] + add2[base + col];
        }
      }
    }
  }
}

// ---------------------------------------------------------------------------
extern "C" void kernel_launch(void* const* d_in, const int* in_sizes, int n_in,
                              void* d_out, int out_size, void* d_ws,
                              size_t ws_size, hipStream_t stream) {
  const float* input = (const float*)d_in[0];
  const float* residual = (const float*)d_in[1];
  const float* bias = (const float*)d_in[3];
  const float* attn_nw = (const float*)d_in[4];
  const float* attn_nb = (const float*)d_in[5];
  const float* inter_w = (const float*)d_in[6];   // [H, DFF]
  const float* inter_b = (const float*)d_in[7];   // [DFF]
  const float* output_w = (const float*)d_in[8];  // [DFF, H]
  const float* output_b = (const float*)d_in[9];  // [H]
  float* out = (float*)d_out;

  char* ws = (char*)d_ws;
  bf16_t* lnb = (bf16_t*)ws;
  bf16_t* w1t = (bf16_t*)(ws + (size_t)NROWS * H_DIM * 2);
  bf16_t* w2t = (bf16_t*)(ws + (size_t)NROWS * H_DIM * 2 +
                          (size_t)H_DIM * DFF_DIM * 2);
  bf16_t* inter = (bf16_t*)(ws + (size_t)NROWS * H_DIM * 2 +
                            2 * (size_t)H_DIM * DFF_DIM * 2);

  fused_ln_kernel<<<NROWS, 256, 0, stream>>>(input, residual, bias, attn_nw,
                                             attn_nb, lnb);
  transpose_cvt_kernel<<<(H_DIM / 64) * (DFF_DIM / 64), 256, 0, stream>>>(
      inter_w, w1t, H_DIM, DFF_DIM);
  transpose_cvt_kernel<<<(DFF_DIM / 64) * (H_DIM / 64), 256, 0, stream>>>(
      output_w, w2t, DFF_DIM, H_DIM);
  gemm8p_kernel<0><<<(NROWS / 256) * (DFF_DIM / 256), 512, 0, stream>>>(
      lnb, w1t, NROWS, DFF_DIM, H_DIM, inter_b, nullptr, nullptr, nullptr,
      inter, nullptr);
  gemm8p_kernel<1><<<(NROWS / 256) * (H_DIM / 256), 512, 0, stream>>>(
      inter, w2t, NROWS, H_DIM, DFF_DIM, bias, output_b, residual, input,
      nullptr, out);
}

// Round 5
// 1201.270 us; speedup vs baseline: 1.2448x; 1.2448x over previous
//
#include <hip/hip_runtime.h>
#include <cstdint>
#include <cstddef>

#define H_DIM 4096
#define DFF_DIM 16384
#define NROWS 4096  // B*S = 2*2048

typedef unsigned short bf16_t;
typedef __attribute__((ext_vector_type(8))) short bf16x8;
typedef __attribute__((ext_vector_type(4))) float f32x4;
typedef __attribute__((ext_vector_type(4))) unsigned short u16x4;

static __device__ __forceinline__ bf16_t f2bf(float f) {
  union { float f; unsigned int i; } v; v.f = f;
  unsigned int x = v.i;
  return (bf16_t)((x + 0x7fffu + ((x >> 16) & 1u)) >> 16);  // RNE
}

// global -> LDS direct async copy, 16B per lane (wave-uniform base + lane*16).
#define GLDS16(gp, lp)                                                    \
  __builtin_amdgcn_global_load_lds(                                       \
      (__attribute__((address_space(1))) void*)(gp),                      \
      (__attribute__((address_space(3))) void*)(lp), 16, 0, 0)

#define SB0 __builtin_amdgcn_sched_barrier(0)

// ---------------------------------------------------------------------------
// Kernel 1: ln_in = input + residual + bias; LN(ln_in, gamma, beta) -> bf16
// ---------------------------------------------------------------------------
__global__ __launch_bounds__(256) void fused_ln_kernel(
    const float* __restrict__ inp, const float* __restrict__ res,
    const float* __restrict__ bias, const float* __restrict__ gamma,
    const float* __restrict__ beta, bf16_t* __restrict__ out) {
  int row = blockIdx.x;
  int t = threadIdx.x;
  const float4* pin = (const float4*)(inp + (size_t)row * H_DIM);
  const float4* pre = (const float4*)(res + (size_t)row * H_DIM);
  const float4* pbi = (const float4*)bias;
  float4 xv[4];
  float s = 0.f, ss = 0.f;
#pragma unroll
  for (int i = 0; i < 4; ++i) {
    int idx = t + i * 256;
    float4 a = pin[idx];
    float4 b = pre[idx];
    float4 c = pbi[idx];
    float4 v;
    v.x = a.x + b.x + c.x;
    v.y = a.y + b.y + c.y;
    v.z = a.z + b.z + c.z;
    v.w = a.w + b.w + c.w;
    xv[i] = v;
    s += v.x + v.y + v.z + v.w;
    ss += v.x * v.x + v.y * v.y + v.z * v.z + v.w * v.w;
  }
#pragma unroll
  for (int off = 32; off > 0; off >>= 1) {
    s += __shfl_xor(s, off);
    ss += __shfl_xor(ss, off);
  }
  __shared__ float sred[8];
  int w = t >> 6, l = t & 63;
  if (l == 0) { sred[w] = s; sred[4 + w] = ss; }
  __syncthreads();
  s = sred[0] + sred[1] + sred[2] + sred[3];
  ss = sred[4] + sred[5] + sred[6] + sred[7];
  const float inv = 1.f / (float)H_DIM;
  float mean = s * inv;
  float var = ss * inv - mean * mean;
  float rstd = rsqrtf(var + 1e-5f);
  const float4* pg = (const float4*)gamma;
  const float4* pb = (const float4*)beta;
#pragma unroll
  for (int i = 0; i < 4; ++i) {
    int idx = t + i * 256;
    float4 g = pg[idx];
    float4 bb = pb[idx];
    float4 v = xv[i];
    u16x4 o;
    o.x = f2bf((v.x - mean) * rstd * g.x + bb.x);
    o.y = f2bf((v.y - mean) * rstd * g.y + bb.y);
    o.z = f2bf((v.z - mean) * rstd * g.z + bb.z);
    o.w = f2bf((v.w - mean) * rstd * g.w + bb.w);
    *(u16x4*)(out + (size_t)row * H_DIM + (size_t)idx * 4) = o;
  }
}

// ---------------------------------------------------------------------------
// Kernel 2: W fp32 [K,N] -> Wt bf16 [N,K] (transpose + convert).
// ---------------------------------------------------------------------------
__global__ __launch_bounds__(256) void transpose_cvt_kernel(
    const float* __restrict__ W, bf16_t* __restrict__ Wt, int K, int N) {
  __shared__ float tile[64][65];
  int nb = N >> 6;
  int bk = blockIdx.x / nb;
  int bn = blockIdx.x - bk * nb;
  int t = threadIdx.x;
  int r = t >> 4;
  int c4 = (t & 15) << 2;
#pragma unroll
  for (int p = 0; p < 4; ++p) {
    int row = r + p * 16;
    float4 v = *(const float4*)(W + (size_t)(bk * 64 + row) * N + bn * 64 + c4);
    tile[row][c4 + 0] = v.x;
    tile[row][c4 + 1] = v.y;
    tile[row][c4 + 2] = v.z;
    tile[row][c4 + 3] = v.w;
  }
  __syncthreads();
#pragma unroll
  for (int p = 0; p < 4; ++p) {
    int nn = r + p * 16;
    u16x4 o;
    o.x = f2bf(tile[c4 + 0][nn]);
    o.y = f2bf(tile[c4 + 1][nn]);
    o.z = f2bf(tile[c4 + 2][nn]);
    o.w = f2bf(tile[c4 + 3][nn]);
    *(u16x4*)(Wt + (size_t)(bn * 64 + nn) * K + bk * 64 + c4) = o;
  }
}

// ---------------------------------------------------------------------------
// Kernel 3: 256x256-tile bf16 GEMM (C = A[M,K] * Bt[N,K]^T), fp32 acc.
// Identical schedule to R4 (passing): 8 waves, A triple-buffered, B double-
// buffered, 4 phases/K-tile, one vmcnt(8)/tile, SB0 pins, XOR swizzle.
// CHANGED (R5): block->tile map. 32-wg co-scheduled chunks are now shaped
// 8(tm) x 4(tn) instead of 16x2: per-chunk panel footprint 36->24 MB, and
// the per-K-tile L2 window is 12 x 32KB = 384 KB (~10 windows of drift slack
// in 4 MB XCD L2) -> cuts A-panel re-fetching across rounds/drift.
// EPI 0: out_bf16 = gelu_tanh(C + eb1[n])
// EPI 1: out_f32  = C + eb1[n] + eb2[n] + add1[m,n] + add2[m,n]
// ---------------------------------------------------------------------------
#define PHASE_TAIL(MIBASE)                                                  \
  __builtin_amdgcn_s_barrier();                                             \
  asm volatile("s_waitcnt lgkmcnt(0)" ::: "memory");                        \
  __builtin_amdgcn_sched_barrier(0);                                        \
  __builtin_amdgcn_s_setprio(1);                                            \
  _Pragma("unroll") for (int ii = 0; ii < 4; ++ii)                          \
      _Pragma("unroll") for (int jj = 0; jj < 4; ++jj) acc[MIBASE + ii][jj] = \
      __builtin_amdgcn_mfma_f32_16x16x32_bf16(aF[ii], bF[jj],               \
                                              acc[MIBASE + ii][jj], 0, 0, 0); \
  __builtin_amdgcn_s_setprio(0);                                            \
  __builtin_amdgcn_s_barrier();

template <int EPI>
__global__ __launch_bounds__(512, 2) void gemm8p_kernel(
    const bf16_t* __restrict__ A, const bf16_t* __restrict__ Bt,
    int M, int N, int K,
    const float* __restrict__ eb1, const float* __restrict__ eb2,
    const float* __restrict__ add1, const float* __restrict__ add2,
    bf16_t* __restrict__ outb, float* __restrict__ outf) {
  __shared__ char lds[163840];  // A: 3 x 32KB @0, B: 2 x 32KB @98304

  const int t = threadIdx.x;
  const int l = t & 63;
  const int wid = t >> 6;
  const int wr = wid >> 2;  // 0..1
  const int wc = wid & 3;   // 0..3

  // Block -> tile: XCD chunk swizzle, then 32-wg chunks shaped 8(tm)x4(tn).
  int nwg = gridDim.x;
  int bid = blockIdx.x;
  int wg = (bid & 7) * (nwg >> 3) + (bid >> 3);
  int ntm = M >> 8;                 // tiles along M (16)
  int chunk = wg >> 5, s5 = wg & 31;
  int cmn = ntm >> 3;               // chunks along tm (2)
  int cm = chunk % cmn, cn = chunk / cmn;
  int tm = cm * 8 + (s5 & 7);
  int tn = cn * 4 + (s5 >> 3);
  size_t m0 = (size_t)tm * 256, n0 = (size_t)tn * 256;

  f32x4 acc[8][4];
#pragma unroll
  for (int i = 0; i < 8; ++i)
#pragma unroll
    for (int j = 0; j < 4; ++j) acc[i][j] = {0.f, 0.f, 0.f, 0.f};

  // Staging: half-tile = 256 rows x 32 k (16KB) = 1024 chunks of 16B.
  // Thread t covers chunks t and t+512 (LDS linear). Source k-slot pre-XORed.
  const int c0 = t, c1 = t + 512;
  const int row0 = c0 >> 2, row1 = c1 >> 2;
  const int ks0 = (c0 & 3) ^ ((row0 >> 1) & 3);
  const int ks1 = (c1 & 3) ^ ((row1 >> 1) & 3);
  const bf16_t* pA0 = A + (m0 + row0) * (size_t)K + ks0 * 8;
  const bf16_t* pA1 = A + (m0 + row1) * (size_t)K + ks1 * 8;
  const bf16_t* pB0 = Bt + (n0 + row0) * (size_t)K + ks0 * 8;
  const bf16_t* pB1 = Bt + (n0 + row1) * (size_t)K + ks1 * 8;

  auto stageA = [&](int base, int h, int T) {
    GLDS16(pA0 + (size_t)T * 64 + h * 32, lds + base + h * 16384 + c0 * 16);
    GLDS16(pA1 + (size_t)T * 64 + h * 32, lds + base + h * 16384 + c1 * 16);
  };
  auto stageB = [&](int base, int h, int T) {
    GLDS16(pB0 + (size_t)T * 64 + h * 32, lds + base + h * 16384 + c0 * 16);
    GLDS16(pB1 + (size_t)T * 64 + h * 32, lds + base + h * 16384 + c1 * 16);
  };

  // ds_read offsets: lane reads row=(base+(l&15)), k-octet (l>>4); physical
  // slot = (l>>4) ^ ((row>>1)&3) = (l>>4) ^ ((l>>1)&3)  (bases are 16-aligned).
  const int slot = (((l >> 4) ^ ((l >> 1) & 3)) << 4);
  int aoffs[8], boffs[4];
#pragma unroll
  for (int mi = 0; mi < 8; ++mi)
    aoffs[mi] = (wr * 128 + mi * 16 + (l & 15)) * 64 + slot;
#pragma unroll
  for (int nj = 0; nj < 4; ++nj)
    boffs[nj] = (wc * 64 + nj * 16 + (l & 15)) * 64 + slot;

  auto rd8 = [&](int off) -> bf16x8 {
    return *(const bf16x8*)(const void*)(lds + off);
  };

  const int NT = K >> 6;  // K-tiles of 64

  // Prologue: tile0 -> A[0]/B[0], tile1 -> A[1]/B[1] (16 loads).
  // vmcnt(8) retires tile0's 8 loads (consumed from T=0.P1).
  stageA(0, 0, 0);
  stageB(98304, 0, 0);
  stageA(0, 1, 0);
  stageB(98304, 1, 0);
  stageA(32768, 0, 1);
  stageB(98304 + 32768, 0, 1);
  stageA(32768, 1, 1);
  stageB(98304 + 32768, 1, 1);
  SB0;
  asm volatile("s_waitcnt vmcnt(8)" ::: "memory");
  SB0;
  __builtin_amdgcn_s_barrier();

  int aC = 0, aS = 2;  // A read-buffer index, A stage-buffer index ((T+2)%3)
  for (int T = 0; T < NT; ++T) {
    const int bB = 98304 + (T & 1) * 32768;   // B buffer (parity of T == T+2)
    const int aCb = aC * 32768;
    const int aSb = aS * 32768;
    int Tg = T + 2;
    if (Tg >= NT) Tg = NT - 1;  // tail: dead prefetch (never consumed)
    bf16x8 aF[4], bF[4];
    // P1: kk0 — B nj0-3 + A mi0-3; stage A[T+2] H0
#pragma unroll
    for (int j = 0; j < 4; ++j) bF[j] = rd8(bB + boffs[j]);
#pragma unroll
    for (int i2 = 0; i2 < 4; ++i2) aF[i2] = rd8(aCb + aoffs[i2]);
    stageA(aSb, 0, Tg);
    SB0;
    PHASE_TAIL(0)
    // P2: kk0 — A mi4-7 (bF reused); stage B[T+2] H0
#pragma unroll
    for (int i2 = 0; i2 < 4; ++i2) aF[i2] = rd8(aCb + aoffs[4 + i2]);
    stageB(bB, 0, Tg);
    SB0;
    PHASE_TAIL(4)
    // P3: kk1 — B + A mi0-3; stage A[T+2] H1
#pragma unroll
    for (int j = 0; j < 4; ++j) bF[j] = rd8(bB + boffs[j] + 16384);
#pragma unroll
    for (int i2 = 0; i2 < 4; ++i2) aF[i2] = rd8(aCb + aoffs[i2] + 16384);
    stageA(aSb, 1, Tg);
    SB0;
    PHASE_TAIL(0)
    // P4: kk1 — A mi4-7; stage B[T+2] H1; ONE wait/tile: vmcnt(8) retires
    // exactly the previous tile's 4 stages (tile T+1 data, ages 4-7 phases).
#pragma unroll
    for (int i2 = 0; i2 < 4; ++i2) aF[i2] = rd8(aCb + aoffs[4 + i2] + 16384);
    stageB(bB, 1, Tg);
    SB0;
    asm volatile("s_waitcnt vmcnt(8)" ::: "memory");
    SB0;
    PHASE_TAIL(4)
    // rotate A buffers: next read buf = aC+1 (mod 3); next stage buf = old aC
    aS = aC;
    aC = (aC == 2) ? 0 : aC + 1;
  }
  asm volatile("s_waitcnt vmcnt(0)" ::: "memory");

  // Epilogue. C/D: col = lane&15, row = (lane>>4)*4 + reg.
  int mb = (int)m0 + wr * 128;
  int nb2 = (int)n0 + wc * 64;
  int lr = (l >> 4) * 4;
  int lc = l & 15;
#pragma unroll
  for (int mi = 0; mi < 8; ++mi) {
#pragma unroll
    for (int i2 = 0; i2 < 4; ++i2) {
      int rrow = mb + mi * 16 + lr + i2;
      size_t base = (size_t)rrow * N;
#pragma unroll
      for (int nj = 0; nj < 4; ++nj) {
        int col = nb2 + nj * 16 + lc;
        float v = acc[mi][nj][i2];
        if (EPI == 0) {
          float x = v + eb1[col];
          float u = 0.7978845608028654f * (x + 0.044715f * x * x * x);
          float th = 1.f - 2.f / (__expf(2.f * u) + 1.f);  // tanh(u)
          outb[base + col] = f2bf(0.5f * x * (1.f + th));
        } else {
          outf[base + col] =
              v + eb1[col] + eb2[col] + add1[base + col] + add2[base + col];
        }
      }
    }
  }
}

// ---------------------------------------------------------------------------
extern "C" void kernel_launch(void* const* d_in, const int* in_sizes, int n_in,
                              void* d_out, int out_size, void* d_ws,
                              size_t ws_size, hipStream_t stream) {
  const float* input = (const float*)d_in[0];
  const float* residual = (const float*)d_in[1];
  const float* bias = (const float*)d_in[3];
  const float* attn_nw = (const float*)d_in[4];
  const float* attn_nb = (const float*)d_in[5];
  const float* inter_w = (const float*)d_in[6];   // [H, DFF]
  const float* inter_b = (const float*)d_in[7];   // [DFF]
  const float* output_w = (const float*)d_in[8];  // [DFF, H]
  const float* output_b = (const float*)d_in[9];  // [H]
  float* out = (float*)d_out;

  char* ws = (char*)d_ws;
  bf16_t* lnb = (bf16_t*)ws;
  bf16_t* w1t = (bf16_t*)(ws + (size_t)NROWS * H_DIM * 2);
  bf16_t* w2t = (bf16_t*)(ws + (size_t)NROWS * H_DIM * 2 +
                          (size_t)H_DIM * DFF_DIM * 2);
  bf16_t* inter = (bf16_t*)(ws + (size_t)NROWS * H_DIM * 2 +
                            2 * (size_t)H_DIM * DFF_DIM * 2);

  fused_ln_kernel<<<NROWS, 256, 0, stream>>>(input, residual, bias, attn_nw,
                                             attn_nb, lnb);
  transpose_cvt_kernel<<<(H_DIM / 64) * (DFF_DIM / 64), 256, 0, stream>>>(
      inter_w, w1t, H_DIM, DFF_DIM);
  transpose_cvt_kernel<<<(DFF_DIM / 64) * (H_DIM / 64), 256, 0, stream>>>(
      output_w, w2t, DFF_DIM, H_DIM);
  gemm8p_kernel<0><<<(NROWS / 256) * (DFF_DIM / 256), 512, 0, stream>>>(
      lnb, w1t, NROWS, DFF_DIM, H_DIM, inter_b, nullptr, nullptr, nullptr,
      inter, nullptr);
  gemm8p_kernel<1><<<(NROWS / 256) * (H_DIM / 256), 512, 0, stream>>>(
      inter, w2t, NROWS, H_DIM, DFF_DIM, bias, output_b, residual, input,
      nullptr, out);
}

// Round 6
// 1198.103 us; speedup vs baseline: 1.2480x; 1.0026x over previous
//
#include <hip/hip_runtime.h>
#include <cstdint>
#include <cstddef>

#define H_DIM 4096
#define DFF_DIM 16384
#define NROWS 4096  // B*S = 2*2048

typedef unsigned short bf16_t;
typedef __attribute__((ext_vector_type(8))) short bf16x8;
typedef __attribute__((ext_vector_type(4))) float f32x4;
typedef __attribute__((ext_vector_type(4))) unsigned short u16x4;

static __device__ __forceinline__ bf16_t f2bf(float f) {
  union { float f; unsigned int i; } v; v.f = f;
  unsigned int x = v.i;
  return (bf16_t)((x + 0x7fffu + ((x >> 16) & 1u)) >> 16);  // RNE
}

// global -> LDS direct async copy, 16B per lane (wave-uniform base + lane*16).
#define GLDS16(gp, lp)                                                    \
  __builtin_amdgcn_global_load_lds(                                       \
      (__attribute__((address_space(1))) void*)(gp),                      \
      (__attribute__((address_space(3))) void*)(lp), 16, 0, 0)

#define SB0 __builtin_amdgcn_sched_barrier(0)

// ---------------------------------------------------------------------------
// Kernel 1: ln_in = input + residual + bias; LN(ln_in, gamma, beta) -> bf16
// ---------------------------------------------------------------------------
__global__ __launch_bounds__(256) void fused_ln_kernel(
    const float* __restrict__ inp, const float* __restrict__ res,
    const float* __restrict__ bias, const float* __restrict__ gamma,
    const float* __restrict__ beta, bf16_t* __restrict__ out) {
  int row = blockIdx.x;
  int t = threadIdx.x;
  const float4* pin = (const float4*)(inp + (size_t)row * H_DIM);
  const float4* pre = (const float4*)(res + (size_t)row * H_DIM);
  const float4* pbi = (const float4*)bias;
  float4 xv[4];
  float s = 0.f, ss = 0.f;
#pragma unroll
  for (int i = 0; i < 4; ++i) {
    int idx = t + i * 256;
    float4 a = pin[idx];
    float4 b = pre[idx];
    float4 c = pbi[idx];
    float4 v;
    v.x = a.x + b.x + c.x;
    v.y = a.y + b.y + c.y;
    v.z = a.z + b.z + c.z;
    v.w = a.w + b.w + c.w;
    xv[i] = v;
    s += v.x + v.y + v.z + v.w;
    ss += v.x * v.x + v.y * v.y + v.z * v.z + v.w * v.w;
  }
#pragma unroll
  for (int off = 32; off > 0; off >>= 1) {
    s += __shfl_xor(s, off);
    ss += __shfl_xor(ss, off);
  }
  __shared__ float sred[8];
  int w = t >> 6, l = t & 63;
  if (l == 0) { sred[w] = s; sred[4 + w] = ss; }
  __syncthreads();
  s = sred[0] + sred[1] + sred[2] + sred[3];
  ss = sred[4] + sred[5] + sred[6] + sred[7];
  const float inv = 1.f / (float)H_DIM;
  float mean = s * inv;
  float var = ss * inv - mean * mean;
  float rstd = rsqrtf(var + 1e-5f);
  const float4* pg = (const float4*)gamma;
  const float4* pb = (const float4*)beta;
#pragma unroll
  for (int i = 0; i < 4; ++i) {
    int idx = t + i * 256;
    float4 g = pg[idx];
    float4 bb = pb[idx];
    float4 v = xv[i];
    u16x4 o;
    o.x = f2bf((v.x - mean) * rstd * g.x + bb.x);
    o.y = f2bf((v.y - mean) * rstd * g.y + bb.y);
    o.z = f2bf((v.z - mean) * rstd * g.z + bb.z);
    o.w = f2bf((v.w - mean) * rstd * g.w + bb.w);
    *(u16x4*)(out + (size_t)row * H_DIM + (size_t)idx * 4) = o;
  }
}

// ---------------------------------------------------------------------------
// Kernel 2: W fp32 [K,N] -> Wt bf16 [N,K] (transpose + convert).
// ---------------------------------------------------------------------------
__global__ __launch_bounds__(256) void transpose_cvt_kernel(
    const float* __restrict__ W, bf16_t* __restrict__ Wt, int K, int N) {
  __shared__ float tile[64][65];
  int nb = N >> 6;
  int bk = blockIdx.x / nb;
  int bn = blockIdx.x - bk * nb;
  int t = threadIdx.x;
  int r = t >> 4;
  int c4 = (t & 15) << 2;
#pragma unroll
  for (int p = 0; p < 4; ++p) {
    int row = r + p * 16;
    float4 v = *(const float4*)(W + (size_t)(bk * 64 + row) * N + bn * 64 + c4);
    tile[row][c4 + 0] = v.x;
    tile[row][c4 + 1] = v.y;
    tile[row][c4 + 2] = v.z;
    tile[row][c4 + 3] = v.w;
  }
  __syncthreads();
#pragma unroll
  for (int p = 0; p < 4; ++p) {
    int nn = r + p * 16;
    u16x4 o;
    o.x = f2bf(tile[c4 + 0][nn]);
    o.y = f2bf(tile[c4 + 1][nn]);
    o.z = f2bf(tile[c4 + 2][nn]);
    o.w = f2bf(tile[c4 + 3][nn]);
    *(u16x4*)(Wt + (size_t)(bn * 64 + nn) * K + bk * 64 + c4) = o;
  }
}

// ---------------------------------------------------------------------------
// Kernel 3: 256x256-tile bf16 GEMM (C = A[M,K] * Bt[N,K]^T), fp32 acc.
// R6: de-fenced schedule. Same stage map / buffers / swizzle / chunk map as
// R5 (passing), but: ONE barrier per phase (post-MFMA), NO lgkmcnt(0) drains
// (ds_reads are IR loads -> compiler emits minimal progressive lgkm waits
// before each MFMA), SB0 only around the per-tile vmcnt. Correctness:
//  - every phase-read is consumed by that phase's MFMAs (data dep), so all
//    reads complete before the phase-end barrier -> stages issued in the
//    NEXT phase body can never clobber un-consumed data (WAR safe);
//  - vmcnt(8) (after P4's MFMAs, SB0-pinned) + tile-boundary barrier give
//    the shared-LDS retire-sync before next tile's P1 reads.
// EPI 0: out_bf16 = gelu_tanh(C + eb1[n])
// EPI 1: out_f32  = C + eb1[n] + eb2[n] + add1[m,n] + add2[m,n]
// ---------------------------------------------------------------------------
#define PHASE_MFMA(MIBASE)                                                  \
  __builtin_amdgcn_s_setprio(1);                                            \
  _Pragma("unroll") for (int ii = 0; ii < 4; ++ii)                          \
      _Pragma("unroll") for (int jj = 0; jj < 4; ++jj) acc[MIBASE + ii][jj] = \
      __builtin_amdgcn_mfma_f32_16x16x32_bf16(aF[ii], bF[jj],               \
                                              acc[MIBASE + ii][jj], 0, 0, 0); \
  __builtin_amdgcn_s_setprio(0);

template <int EPI>
__global__ __launch_bounds__(512, 2) void gemm8p_kernel(
    const bf16_t* __restrict__ A, const bf16_t* __restrict__ Bt,
    int M, int N, int K,
    const float* __restrict__ eb1, const float* __restrict__ eb2,
    const float* __restrict__ add1, const float* __restrict__ add2,
    bf16_t* __restrict__ outb, float* __restrict__ outf) {
  __shared__ char lds[163840];  // A: 3 x 32KB @0, B: 2 x 32KB @98304

  const int t = threadIdx.x;
  const int l = t & 63;
  const int wid = t >> 6;
  const int wr = wid >> 2;  // 0..1
  const int wc = wid & 3;   // 0..3

  // Block -> tile: XCD chunk swizzle, then 32-wg chunks shaped 8(tm)x4(tn).
  int nwg = gridDim.x;
  int bid = blockIdx.x;
  int wg = (bid & 7) * (nwg >> 3) + (bid >> 3);
  int ntm = M >> 8;                 // tiles along M (16)
  int chunk = wg >> 5, s5 = wg & 31;
  int cmn = ntm >> 3;               // chunks along tm (2)
  int cm = chunk % cmn, cn = chunk / cmn;
  int tm = cm * 8 + (s5 & 7);
  int tn = cn * 4 + (s5 >> 3);
  size_t m0 = (size_t)tm * 256, n0 = (size_t)tn * 256;

  f32x4 acc[8][4];
#pragma unroll
  for (int i = 0; i < 8; ++i)
#pragma unroll
    for (int j = 0; j < 4; ++j) acc[i][j] = {0.f, 0.f, 0.f, 0.f};

  // Staging: half-tile = 256 rows x 32 k (16KB) = 1024 chunks of 16B.
  // Thread t covers chunks t and t+512 (LDS linear). Source k-slot pre-XORed.
  const int c0 = t, c1 = t + 512;
  const int row0 = c0 >> 2, row1 = c1 >> 2;
  const int ks0 = (c0 & 3) ^ ((row0 >> 1) & 3);
  const int ks1 = (c1 & 3) ^ ((row1 >> 1) & 3);
  const bf16_t* pA0 = A + (m0 + row0) * (size_t)K + ks0 * 8;
  const bf16_t* pA1 = A + (m0 + row1) * (size_t)K + ks1 * 8;
  const bf16_t* pB0 = Bt + (n0 + row0) * (size_t)K + ks0 * 8;
  const bf16_t* pB1 = Bt + (n0 + row1) * (size_t)K + ks1 * 8;

  auto stageA = [&](int base, int h, int T) {
    GLDS16(pA0 + (size_t)T * 64 + h * 32, lds + base + h * 16384 + c0 * 16);
    GLDS16(pA1 + (size_t)T * 64 + h * 32, lds + base + h * 16384 + c1 * 16);
  };
  auto stageB = [&](int base, int h, int T) {
    GLDS16(pB0 + (size_t)T * 64 + h * 32, lds + base + h * 16384 + c0 * 16);
    GLDS16(pB1 + (size_t)T * 64 + h * 32, lds + base + h * 16384 + c1 * 16);
  };

  // ds_read offsets: lane reads row=(base+(l&15)), k-octet (l>>4); physical
  // slot = (l>>4) ^ ((row>>1)&3) = (l>>4) ^ ((l>>1)&3)  (bases are 16-aligned).
  const int slot = (((l >> 4) ^ ((l >> 1) & 3)) << 4);
  int aoffs[8], boffs[4];
#pragma unroll
  for (int mi = 0; mi < 8; ++mi)
    aoffs[mi] = (wr * 128 + mi * 16 + (l & 15)) * 64 + slot;
#pragma unroll
  for (int nj = 0; nj < 4; ++nj)
    boffs[nj] = (wc * 64 + nj * 16 + (l & 15)) * 64 + slot;

  auto rd8 = [&](int off) -> bf16x8 {
    return *(const bf16x8*)(const void*)(lds + off);
  };

  const int NT = K >> 6;  // K-tiles of 64

  // Prologue: tile0 -> A[0]/B[0], tile1 -> A[1]/B[1] (16 loads).
  // vmcnt(8) retires tile0's 8 loads (consumed from T=0.P1).
  stageA(0, 0, 0);
  stageB(98304, 0, 0);
  stageA(0, 1, 0);
  stageB(98304, 1, 0);
  stageA(32768, 0, 1);
  stageB(98304 + 32768, 0, 1);
  stageA(32768, 1, 1);
  stageB(98304 + 32768, 1, 1);
  SB0;
  asm volatile("s_waitcnt vmcnt(8)" ::: "memory");
  SB0;
  __builtin_amdgcn_s_barrier();

  int aC = 0, aS = 2;  // A read-buffer index, A stage-buffer index ((T+2)%3)
  for (int T = 0; T < NT; ++T) {
    const int bB = 98304 + (T & 1) * 32768;   // B buffer (parity of T == T+2)
    const int aCb = aC * 32768;
    const int aSb = aS * 32768;
    int Tg = T + 2;
    if (Tg >= NT) Tg = NT - 1;  // tail: dead prefetch (never consumed)
    bf16x8 aF[4], bF[4];
    // P1: kk0 — B nj0-3 + A mi0-3; stage A[T+2] H0
#pragma unroll
    for (int j = 0; j < 4; ++j) bF[j] = rd8(bB + boffs[j]);
#pragma unroll
    for (int i2 = 0; i2 < 4; ++i2) aF[i2] = rd8(aCb + aoffs[i2]);
    stageA(aSb, 0, Tg);
    PHASE_MFMA(0)
    __builtin_amdgcn_s_barrier();
    // P2: kk0 — A mi4-7 (bF reused); stage B[T+2] H0 (kk0-B consumed in P1)
#pragma unroll
    for (int i2 = 0; i2 < 4; ++i2) aF[i2] = rd8(aCb + aoffs[4 + i2]);
    stageB(bB, 0, Tg);
    PHASE_MFMA(4)
    __builtin_amdgcn_s_barrier();
    // P3: kk1 — B + A mi0-3; stage A[T+2] H1
#pragma unroll
    for (int j = 0; j < 4; ++j) bF[j] = rd8(bB + boffs[j] + 16384);
#pragma unroll
    for (int i2 = 0; i2 < 4; ++i2) aF[i2] = rd8(aCb + aoffs[i2] + 16384);
    stageA(aSb, 1, Tg);
    PHASE_MFMA(0)
    __builtin_amdgcn_s_barrier();
    // P4: kk1 — A mi4-7; stage B[T+2] H1 (kk1-B consumed in P3).
    // vmcnt(8) AFTER the MFMAs (retire-wait overlaps compute): retires the
    // previous tile's 4 stages (tile T+1 data, issued 4-7 phases ago);
    // tile-boundary barrier makes them visible to all waves.
#pragma unroll
    for (int i2 = 0; i2 < 4; ++i2) aF[i2] = rd8(aCb + aoffs[4 + i2] + 16384);
    stageB(bB, 1, Tg);
    PHASE_MFMA(4)
    SB0;
    asm volatile("s_waitcnt vmcnt(8)" ::: "memory");
    SB0;
    __builtin_amdgcn_s_barrier();
    // rotate A buffers: next read buf = aC+1 (mod 3); next stage buf = old aC
    aS = aC;
    aC = (aC == 2) ? 0 : aC + 1;
  }
  asm volatile("s_waitcnt vmcnt(0)" ::: "memory");

  // Epilogue. C/D: col = lane&15, row = (lane>>4)*4 + reg.
  int mb = (int)m0 + wr * 128;
  int nb2 = (int)n0 + wc * 64;
  int lr = (l >> 4) * 4;
  int lc = l & 15;
#pragma unroll
  for (int mi = 0; mi < 8; ++mi) {
#pragma unroll
    for (int i2 = 0; i2 < 4; ++i2) {
      int rrow = mb + mi * 16 + lr + i2;
      size_t base = (size_t)rrow * N;
#pragma unroll
      for (int nj = 0; nj < 4; ++nj) {
        int col = nb2 + nj * 16 + lc;
        float v = acc[mi][nj][i2];
        if (EPI == 0) {
          float x = v + eb1[col];
          float u = 0.7978845608028654f * (x + 0.044715f * x * x * x);
          float th = 1.f - 2.f / (__expf(2.f * u) + 1.f);  // tanh(u)
          outb[base + col] = f2bf(0.5f * x * (1.f + th));
        } else {
          outf[base + col] =
              v + eb1[col] + eb2[col] + add1[base + col] + add2[base + col];
        }
      }
    }
  }
}

// ---------------------------------------------------------------------------
extern "C" void kernel_launch(void* const* d_in, const int* in_sizes, int n_in,
                              void* d_out, int out_size, void* d_ws,
                              size_t ws_size, hipStream_t stream) {
  const float* input = (const float*)d_in[0];
  const float* residual = (const float*)d_in[1];
  const float* bias = (const float*)d_in[3];
  const float* attn_nw = (const float*)d_in[4];
  const float* attn_nb = (const float*)d_in[5];
  const float* inter_w = (const float*)d_in[6];   // [H, DFF]
  const float* inter_b = (const float*)d_in[7];   // [DFF]
  const float* output_w = (const float*)d_in[8];  // [DFF, H]
  const float* output_b = (const float*)d_in[9];  // [H]
  float* out = (float*)d_out;

  char* ws = (char*)d_ws;
  bf16_t* lnb = (bf16_t*)ws;
  bf16_t* w1t = (bf16_t*)(ws + (size_t)NROWS * H_DIM * 2);
  bf16_t* w2t = (bf16_t*)(ws + (size_t)NROWS * H_DIM * 2 +
                          (size_t)H_DIM * DFF_DIM * 2);
  bf16_t* inter = (bf16_t*)(ws + (size_t)NROWS * H_DIM * 2 +
                            2 * (size_t)H_DIM * DFF_DIM * 2);

  fused_ln_kernel<<<NROWS, 256, 0, stream>>>(input, residual, bias, attn_nw,
                                             attn_nb, lnb);
  transpose_cvt_kernel<<<(H_DIM / 64) * (DFF_DIM / 64), 256, 0, stream>>>(
      inter_w, w1t, H_DIM, DFF_DIM);
  transpose_cvt_kernel<<<(DFF_DIM / 64) * (H_DIM / 64), 256, 0, stream>>>(
      output_w, w2t, DFF_DIM, H_DIM);
  gemm8p_kernel<0><<<(NROWS / 256) * (DFF_DIM / 256), 512, 0, stream>>>(
      lnb, w1t, NROWS, DFF_DIM, H_DIM, inter_b, nullptr, nullptr, nullptr,
      inter, nullptr);
  gemm8p_kernel<1><<<(NROWS / 256) * (H_DIM / 256), 512, 0, stream>>>(
      inter, w2t, NROWS, H_DIM, DFF_DIM, bias, output_b, residual, input,
      nullptr, out);
}

// Round 7
// 1191.706 us; speedup vs baseline: 1.2547x; 1.0054x over previous
//
#include <hip/hip_runtime.h>
#include <cstdint>
#include <cstddef>

#define H_DIM 4096
#define DFF_DIM 16384
#define NROWS 4096  // B*S = 2*2048

typedef unsigned short bf16_t;
typedef __attribute__((ext_vector_type(8))) short bf16x8;
typedef __attribute__((ext_vector_type(4))) float f32x4;
typedef __attribute__((ext_vector_type(4))) unsigned short u16x4;

static __device__ __forceinline__ bf16_t f2bf(float f) {
  union { float f; unsigned int i; } v; v.f = f;
  unsigned int x = v.i;
  return (bf16_t)((x + 0x7fffu + ((x >> 16) & 1u)) >> 16);  // RNE
}

// global -> LDS direct async copy, 16B per lane (wave-uniform base + lane*16).
#define GLDS16(gp, lp)                                                    \
  __builtin_amdgcn_global_load_lds(                                       \
      (__attribute__((address_space(1))) void*)(gp),                      \
      (__attribute__((address_space(3))) void*)(lp), 16, 0, 0)

#define SB0 __builtin_amdgcn_sched_barrier(0)

// ---------------------------------------------------------------------------
// Kernel 1: ln_in = input + residual + bias; LN(ln_in, gamma, beta) -> bf16
// ---------------------------------------------------------------------------
__global__ __launch_bounds__(256) void fused_ln_kernel(
    const float* __restrict__ inp, const float* __restrict__ res,
    const float* __restrict__ bias, const float* __restrict__ gamma,
    const float* __restrict__ beta, bf16_t* __restrict__ out) {
  int row = blockIdx.x;
  int t = threadIdx.x;
  const float4* pin = (const float4*)(inp + (size_t)row * H_DIM);
  const float4* pre = (const float4*)(res + (size_t)row * H_DIM);
  const float4* pbi = (const float4*)bias;
  float4 xv[4];
  float s = 0.f, ss = 0.f;
#pragma unroll
  for (int i = 0; i < 4; ++i) {
    int idx = t + i * 256;
    float4 a = pin[idx];
    float4 b = pre[idx];
    float4 c = pbi[idx];
    float4 v;
    v.x = a.x + b.x + c.x;
    v.y = a.y + b.y + c.y;
    v.z = a.z + b.z + c.z;
    v.w = a.w + b.w + c.w;
    xv[i] = v;
    s += v.x + v.y + v.z + v.w;
    ss += v.x * v.x + v.y * v.y + v.z * v.z + v.w * v.w;
  }
#pragma unroll
  for (int off = 32; off > 0; off >>= 1) {
    s += __shfl_xor(s, off);
    ss += __shfl_xor(ss, off);
  }
  __shared__ float sred[8];
  int w = t >> 6, l = t & 63;
  if (l == 0) { sred[w] = s; sred[4 + w] = ss; }
  __syncthreads();
  s = sred[0] + sred[1] + sred[2] + sred[3];
  ss = sred[4] + sred[5] + sred[6] + sred[7];
  const float inv = 1.f / (float)H_DIM;
  float mean = s * inv;
  float var = ss * inv - mean * mean;
  float rstd = rsqrtf(var + 1e-5f);
  const float4* pg = (const float4*)gamma;
  const float4* pb = (const float4*)beta;
#pragma unroll
  for (int i = 0; i < 4; ++i) {
    int idx = t + i * 256;
    float4 g = pg[idx];
    float4 bb = pb[idx];
    float4 v = xv[i];
    u16x4 o;
    o.x = f2bf((v.x - mean) * rstd * g.x + bb.x);
    o.y = f2bf((v.y - mean) * rstd * g.y + bb.y);
    o.z = f2bf((v.z - mean) * rstd * g.z + bb.z);
    o.w = f2bf((v.w - mean) * rstd * g.w + bb.w);
    *(u16x4*)(out + (size_t)row * H_DIM + (size_t)idx * 4) = o;
  }
}

// ---------------------------------------------------------------------------
// Kernel 2: W fp32 [K,N] -> Wt bf16 [N,K] (transpose + convert).
// ---------------------------------------------------------------------------
__global__ __launch_bounds__(256) void transpose_cvt_kernel(
    const float* __restrict__ W, bf16_t* __restrict__ Wt, int K, int N) {
  __shared__ float tile[64][65];
  int nb = N >> 6;
  int bk = blockIdx.x / nb;
  int bn = blockIdx.x - bk * nb;
  int t = threadIdx.x;
  int r = t >> 4;
  int c4 = (t & 15) << 2;
#pragma unroll
  for (int p = 0; p < 4; ++p) {
    int row = r + p * 16;
    float4 v = *(const float4*)(W + (size_t)(bk * 64 + row) * N + bn * 64 + c4);
    tile[row][c4 + 0] = v.x;
    tile[row][c4 + 1] = v.y;
    tile[row][c4 + 2] = v.z;
    tile[row][c4 + 3] = v.w;
  }
  __syncthreads();
#pragma unroll
  for (int p = 0; p < 4; ++p) {
    int nn = r + p * 16;
    u16x4 o;
    o.x = f2bf(tile[c4 + 0][nn]);
    o.y = f2bf(tile[c4 + 1][nn]);
    o.z = f2bf(tile[c4 + 2][nn]);
    o.w = f2bf(tile[c4 + 3][nn]);
    *(u16x4*)(Wt + (size_t)(bn * 64 + nn) * K + bk * 64 + c4) = o;
  }
}

// ---------------------------------------------------------------------------
// Kernel 3: 256x256-tile bf16 GEMM (C = A[M,K] * Bt[N,K]^T), fp32 acc.
// R7: register-level read-ahead pipeline. Same buffers (A 3x32KB, B 2x32KB),
// swizzle, chunk map, stage map as R5/R6 (passing), but each phase issues the
// NEXT phase's ds_reads before its own MFMA cluster -> LDS pipe streams while
// MFMA pipe crunches (previously strictly serial: MfmaUtil 50% = MFMA/(MFMA+
// LDS)). Derived waits:
//  - every phase ends [lgkmcnt(0); s_barrier]: all LDS reads issued up to
//    here are COMPLETE before any later stage can clobber (WAR safe; each
//    stage target's readers drained >=1 phase earlier - audited per stage).
//  - vmcnt(6) at P3-end (ledger: retires exactly tile T-1's 8 loads = tile
//    T+1's full A+B data, ages 4-7 phases) -> P4 may prefetch NEXT tile's
//    P1 operands after the P3-end barrier.
// All fragment regs are named arrays w/ static indices (no scratch).
// EPI 0: out_bf16 = gelu_tanh(C + eb1[n])
// EPI 1: out_f32  = C + eb1[n] + eb2[n] + add1[m,n] + add2[m,n]
// ---------------------------------------------------------------------------
#define MFMA16(AB, BB, MIBASE)                                              \
  __builtin_amdgcn_s_setprio(1);                                            \
  _Pragma("unroll") for (int ii = 0; ii < 4; ++ii)                          \
      _Pragma("unroll") for (int jj = 0; jj < 4; ++jj) acc[MIBASE + ii][jj] = \
      __builtin_amdgcn_mfma_f32_16x16x32_bf16(AB[ii], BB[jj],               \
                                              acc[MIBASE + ii][jj], 0, 0, 0); \
  __builtin_amdgcn_s_setprio(0);

template <int EPI>
__global__ __launch_bounds__(512, 2) void gemm8p_kernel(
    const bf16_t* __restrict__ A, const bf16_t* __restrict__ Bt,
    int M, int N, int K,
    const float* __restrict__ eb1, const float* __restrict__ eb2,
    const float* __restrict__ add1, const float* __restrict__ add2,
    bf16_t* __restrict__ outb, float* __restrict__ outf) {
  __shared__ char lds[163840];  // A: 3 x 32KB @0, B: 2 x 32KB @98304

  const int t = threadIdx.x;
  const int l = t & 63;
  const int wid = t >> 6;
  const int wr = wid >> 2;  // 0..1
  const int wc = wid & 3;   // 0..3

  // Block -> tile: XCD chunk swizzle, then 32-wg chunks shaped 8(tm)x4(tn).
  int nwg = gridDim.x;
  int bid = blockIdx.x;
  int wg = (bid & 7) * (nwg >> 3) + (bid >> 3);
  int ntm = M >> 8;                 // tiles along M (16)
  int chunk = wg >> 5, s5 = wg & 31;
  int cmn = ntm >> 3;               // chunks along tm (2)
  int cm = chunk % cmn, cn = chunk / cmn;
  int tm = cm * 8 + (s5 & 7);
  int tn = cn * 4 + (s5 >> 3);
  size_t m0 = (size_t)tm * 256, n0 = (size_t)tn * 256;

  f32x4 acc[8][4];
#pragma unroll
  for (int i = 0; i < 8; ++i)
#pragma unroll
    for (int j = 0; j < 4; ++j) acc[i][j] = {0.f, 0.f, 0.f, 0.f};

  // Staging: half-tile = 256 rows x 32 k (16KB) = 1024 chunks of 16B.
  // Thread t covers chunks t and t+512 (LDS linear). Source k-slot pre-XORed.
  const int c0 = t, c1 = t + 512;
  const int row0 = c0 >> 2, row1 = c1 >> 2;
  const int ks0 = (c0 & 3) ^ ((row0 >> 1) & 3);
  const int ks1 = (c1 & 3) ^ ((row1 >> 1) & 3);
  const bf16_t* pA0 = A + (m0 + row0) * (size_t)K + ks0 * 8;
  const bf16_t* pA1 = A + (m0 + row1) * (size_t)K + ks1 * 8;
  const bf16_t* pB0 = Bt + (n0 + row0) * (size_t)K + ks0 * 8;
  const bf16_t* pB1 = Bt + (n0 + row1) * (size_t)K + ks1 * 8;

  auto stageA = [&](int base, int h, int T) {
    GLDS16(pA0 + (size_t)T * 64 + h * 32, lds + base + h * 16384 + c0 * 16);
    GLDS16(pA1 + (size_t)T * 64 + h * 32, lds + base + h * 16384 + c1 * 16);
  };
  auto stageB = [&](int base, int h, int T) {
    GLDS16(pB0 + (size_t)T * 64 + h * 32, lds + base + h * 16384 + c0 * 16);
    GLDS16(pB1 + (size_t)T * 64 + h * 32, lds + base + h * 16384 + c1 * 16);
  };

  // ds_read offsets: lane reads row=(base+(l&15)), k-octet (l>>4); physical
  // slot = (l>>4) ^ ((row>>1)&3) = (l>>4) ^ ((l>>1)&3)  (bases are 16-aligned).
  const int slot = (((l >> 4) ^ ((l >> 1) & 3)) << 4);
  int aoffs[8], boffs[4];
#pragma unroll
  for (int mi = 0; mi < 8; ++mi)
    aoffs[mi] = (wr * 128 + mi * 16 + (l & 15)) * 64 + slot;
#pragma unroll
  for (int nj = 0; nj < 4; ++nj)
    boffs[nj] = (wc * 64 + nj * 16 + (l & 15)) * 64 + slot;

  auto rd8 = [&](int off) -> bf16x8 {
    return *(const bf16x8*)(const void*)(lds + off);
  };

  const int NT = K >> 6;  // K-tiles of 64

  // Prologue: tile0 -> A[0]/B[0], tile1 -> A[1]/B[1] (16 loads).
  // vmcnt(8) retires tile0's 8 loads; leftover = 8 (tile1's) -> matches the
  // steady-state ledger at the first P3-end vmcnt(6).
  stageA(0, 0, 0);
  stageB(98304, 0, 0);
  stageA(0, 1, 0);
  stageB(98304, 1, 0);
  stageA(32768, 0, 1);
  stageB(98304 + 32768, 0, 1);
  stageA(32768, 1, 1);
  stageB(98304 + 32768, 1, 1);
  SB0;
  asm volatile("s_waitcnt vmcnt(8)" ::: "memory");
  SB0;
  __builtin_amdgcn_s_barrier();

  // Pre-read tile0's P1 operands (B kk0, A-lo kk0).
  bf16x8 bP[4], aL[4], aH[4], bQ[4], aL2[4], aH2[4];
#pragma unroll
  for (int j = 0; j < 4; ++j) bP[j] = rd8(98304 + boffs[j]);
#pragma unroll
  for (int i = 0; i < 4; ++i) aL[i] = rd8(aoffs[i]);

  int aC = 0, aS = 2;  // A read-buffer index, A stage-buffer index ((T+2)%3)
  for (int T = 0; T < NT; ++T) {
    const int bB = 98304 + (T & 1) * 32768;        // B buffer for tile T
    const int bBn = 98304 + ((T + 1) & 1) * 32768; // B buffer for tile T+1
    const int aCb = aC * 32768;
    const int aCn = (aC == 2 ? 0 : aC + 1) * 32768;
    const int aSb = aS * 32768;
    int Tg = T + 2;
    if (Tg >= NT) Tg = NT - 1;  // tail: dead prefetch (never consumed)

    // P1: prefetch A-hi kk0; stage A[T+2].H0; MFMA kk0 x mi0-3 (aL,bP).
#pragma unroll
    for (int i2 = 0; i2 < 4; ++i2) aH[i2] = rd8(aCb + aoffs[4 + i2]);
    stageA(aSb, 0, Tg);
    SB0;
    MFMA16(aL, bP, 0)
    asm volatile("s_waitcnt lgkmcnt(0)" ::: "memory");
    __builtin_amdgcn_s_barrier();

    // P2: prefetch B kk1 + A-lo kk1; stage B[T].H0 <- T+2 (H0 readers drained
    // at P1-end); MFMA kk0 x mi4-7 (aH,bP).
#pragma unroll
    for (int j = 0; j < 4; ++j) bQ[j] = rd8(bB + boffs[j] + 16384);
#pragma unroll
    for (int i2 = 0; i2 < 4; ++i2) aL2[i2] = rd8(aCb + aoffs[i2] + 16384);
    stageB(bB, 0, Tg);
    SB0;
    MFMA16(aH, bP, 4)
    asm volatile("s_waitcnt lgkmcnt(0)" ::: "memory");
    __builtin_amdgcn_s_barrier();

    // P3: prefetch A-hi kk1; stage A[T+2].H1; MFMA kk1 x mi0-3 (aL2,bQ).
    // End: vmcnt(6) retires ALL of tile T-1's 8 loads (= tile T+1's data,
    // ages 4-7 phases) + lgkm drain + barrier -> T+1 buffers readable.
#pragma unroll
    for (int i2 = 0; i2 < 4; ++i2) aH2[i2] = rd8(aCb + aoffs[4 + i2] + 16384);
    stageA(aSb, 1, Tg);
    SB0;
    MFMA16(aL2, bQ, 0)
    SB0;
    asm volatile("s_waitcnt vmcnt(6) lgkmcnt(0)" ::: "memory");
    SB0;
    __builtin_amdgcn_s_barrier();

    // P4: prefetch NEXT tile's P1 operands (B' kk0, A'-lo kk0) from T+1
    // buffers (retired above); stage B[T].H1 <- T+2 (H1 readers drained at
    // P3-end); MFMA kk1 x mi4-7 (aH2,bQ).
#pragma unroll
    for (int j = 0; j < 4; ++j) bP[j] = rd8(bBn + boffs[j]);
#pragma unroll
    for (int i2 = 0; i2 < 4; ++i2) aL[i2] = rd8(aCn + aoffs[i2]);
    stageB(bB, 1, Tg);
    SB0;
    MFMA16(aH2, bQ, 4)
    asm volatile("s_waitcnt lgkmcnt(0)" ::: "memory");
    __builtin_amdgcn_s_barrier();

    // rotate A buffers: next read buf = aC+1 (mod 3); next stage buf = old aC
    aS = aC;
    aC = (aC == 2) ? 0 : aC + 1;
  }
  asm volatile("s_waitcnt vmcnt(0)" ::: "memory");

  // Epilogue. C/D: col = lane&15, row = (lane>>4)*4 + reg.
  int mb = (int)m0 + wr * 128;
  int nb2 = (int)n0 + wc * 64;
  int lr = (l >> 4) * 4;
  int lc = l & 15;
#pragma unroll
  for (int mi = 0; mi < 8; ++mi) {
#pragma unroll
    for (int i2 = 0; i2 < 4; ++i2) {
      int rrow = mb + mi * 16 + lr + i2;
      size_t base = (size_t)rrow * N;
#pragma unroll
      for (int nj = 0; nj < 4; ++nj) {
        int col = nb2 + nj * 16 + lc;
        float v = acc[mi][nj][i2];
        if (EPI == 0) {
          float x = v + eb1[col];
          float u = 0.7978845608028654f * (x + 0.044715f * x * x * x);
          float th = 1.f - 2.f / (__expf(2.f * u) + 1.f);  // tanh(u)
          outb[base + col] = f2bf(0.5f * x * (1.f + th));
        } else {
          outf[base + col] =
              v + eb1[col] + eb2[col] + add1[base + col] + add2[base + col];
        }
      }
    }
  }
}

// ---------------------------------------------------------------------------
extern "C" void kernel_launch(void* const* d_in, const int* in_sizes, int n_in,
                              void* d_out, int out_size, void* d_ws,
                              size_t ws_size, hipStream_t stream) {
  const float* input = (const float*)d_in[0];
  const float* residual = (const float*)d_in[1];
  const float* bias = (const float*)d_in[3];
  const float* attn_nw = (const float*)d_in[4];
  const float* attn_nb = (const float*)d_in[5];
  const float* inter_w = (const float*)d_in[6];   // [H, DFF]
  const float* inter_b = (const float*)d_in[7];   // [DFF]
  const float* output_w = (const float*)d_in[8];  // [DFF, H]
  const float* output_b = (const float*)d_in[9];  // [H]
  float* out = (float*)d_out;

  char* ws = (char*)d_ws;
  bf16_t* lnb = (bf16_t*)ws;
  bf16_t* w1t = (bf16_t*)(ws + (size_t)NROWS * H_DIM * 2);
  bf16_t* w2t = (bf16_t*)(ws + (size_t)NROWS * H_DIM * 2 +
                          (size_t)H_DIM * DFF_DIM * 2);
  bf16_t* inter = (bf16_t*)(ws + (size_t)NROWS * H_DIM * 2 +
                            2 * (size_t)H_DIM * DFF_DIM * 2);

  fused_ln_kernel<<<NROWS, 256, 0, stream>>>(input, residual, bias, attn_nw,
                                             attn_nb, lnb);
  transpose_cvt_kernel<<<(H_DIM / 64) * (DFF_DIM / 64), 256, 0, stream>>>(
      inter_w, w1t, H_DIM, DFF_DIM);
  transpose_cvt_kernel<<<(DFF_DIM / 64) * (H_DIM / 64), 256, 0, stream>>>(
      output_w, w2t, DFF_DIM, H_DIM);
  gemm8p_kernel<0><<<(NROWS / 256) * (DFF_DIM / 256), 512, 0, stream>>>(
      lnb, w1t, NROWS, DFF_DIM, H_DIM, inter_b, nullptr, nullptr, nullptr,
      inter, nullptr);
  gemm8p_kernel<1><<<(NROWS / 256) * (H_DIM / 256), 512, 0, stream>>>(
      inter, w2t, NROWS, H_DIM, DFF_DIM, bias, output_b, residual, input,
      nullptr, out);
}

// Round 8
// 1068.328 us; speedup vs baseline: 1.3997x; 1.1155x over previous
//
#include <hip/hip_runtime.h>
#include <cstdint>
#include <cstddef>

#define H_DIM 4096
#define DFF_DIM 16384
#define NROWS 4096  // B*S = 2*2048

typedef unsigned short bf16_t;
typedef __attribute__((ext_vector_type(8))) short bf16x8;
typedef __attribute__((ext_vector_type(4))) float f32x4;
typedef __attribute__((ext_vector_type(4))) unsigned short u16x4;

static __device__ __forceinline__ bf16_t f2bf(float f) {
  union { float f; unsigned int i; } v; v.f = f;
  unsigned int x = v.i;
  return (bf16_t)((x + 0x7fffu + ((x >> 16) & 1u)) >> 16);  // RNE
}

// global -> LDS direct async copy, 16B per lane (wave-uniform base + lane*16).
#define GLDS16(gp, lp)                                                    \
  __builtin_amdgcn_global_load_lds(                                       \
      (__attribute__((address_space(1))) void*)(gp),                      \
      (__attribute__((address_space(3))) void*)(lp), 16, 0, 0)

#define SB0 __builtin_amdgcn_sched_barrier(0)

// ---------------------------------------------------------------------------
// Kernel 1: ln_in = input + residual + bias; LN(ln_in, gamma, beta) -> bf16
// ---------------------------------------------------------------------------
__global__ __launch_bounds__(256) void fused_ln_kernel(
    const float* __restrict__ inp, const float* __restrict__ res,
    const float* __restrict__ bias, const float* __restrict__ gamma,
    const float* __restrict__ beta, bf16_t* __restrict__ out) {
  int row = blockIdx.x;
  int t = threadIdx.x;
  const float4* pin = (const float4*)(inp + (size_t)row * H_DIM);
  const float4* pre = (const float4*)(res + (size_t)row * H_DIM);
  const float4* pbi = (const float4*)bias;
  float4 xv[4];
  float s = 0.f, ss = 0.f;
#pragma unroll
  for (int i = 0; i < 4; ++i) {
    int idx = t + i * 256;
    float4 a = pin[idx];
    float4 b = pre[idx];
    float4 c = pbi[idx];
    float4 v;
    v.x = a.x + b.x + c.x;
    v.y = a.y + b.y + c.y;
    v.z = a.z + b.z + c.z;
    v.w = a.w + b.w + c.w;
    xv[i] = v;
    s += v.x + v.y + v.z + v.w;
    ss += v.x * v.x + v.y * v.y + v.z * v.z + v.w * v.w;
  }
#pragma unroll
  for (int off = 32; off > 0; off >>= 1) {
    s += __shfl_xor(s, off);
    ss += __shfl_xor(ss, off);
  }
  __shared__ float sred[8];
  int w = t >> 6, l = t & 63;
  if (l == 0) { sred[w] = s; sred[4 + w] = ss; }
  __syncthreads();
  s = sred[0] + sred[1] + sred[2] + sred[3];
  ss = sred[4] + sred[5] + sred[6] + sred[7];
  const float inv = 1.f / (float)H_DIM;
  float mean = s * inv;
  float var = ss * inv - mean * mean;
  float rstd = rsqrtf(var + 1e-5f);
  const float4* pg = (const float4*)gamma;
  const float4* pb = (const float4*)beta;
#pragma unroll
  for (int i = 0; i < 4; ++i) {
    int idx = t + i * 256;
    float4 g = pg[idx];
    float4 bb = pb[idx];
    float4 v = xv[i];
    u16x4 o;
    o.x = f2bf((v.x - mean) * rstd * g.x + bb.x);
    o.y = f2bf((v.y - mean) * rstd * g.y + bb.y);
    o.z = f2bf((v.z - mean) * rstd * g.z + bb.z);
    o.w = f2bf((v.w - mean) * rstd * g.w + bb.w);
    *(u16x4*)(out + (size_t)row * H_DIM + (size_t)idx * 4) = o;
  }
}

// ---------------------------------------------------------------------------
// Kernel 2: W fp32 [K,N] -> Wt bf16 [N,K] (transpose + convert).
// ---------------------------------------------------------------------------
__global__ __launch_bounds__(256) void transpose_cvt_kernel(
    const float* __restrict__ W, bf16_t* __restrict__ Wt, int K, int N) {
  __shared__ float tile[64][65];
  int nb = N >> 6;
  int bk = blockIdx.x / nb;
  int bn = blockIdx.x - bk * nb;
  int t = threadIdx.x;
  int r = t >> 4;
  int c4 = (t & 15) << 2;
#pragma unroll
  for (int p = 0; p < 4; ++p) {
    int row = r + p * 16;
    float4 v = *(const float4*)(W + (size_t)(bk * 64 + row) * N + bn * 64 + c4);
    tile[row][c4 + 0] = v.x;
    tile[row][c4 + 1] = v.y;
    tile[row][c4 + 2] = v.z;
    tile[row][c4 + 3] = v.w;
  }
  __syncthreads();
#pragma unroll
  for (int p = 0; p < 4; ++p) {
    int nn = r + p * 16;
    u16x4 o;
    o.x = f2bf(tile[c4 + 0][nn]);
    o.y = f2bf(tile[c4 + 1][nn]);
    o.z = f2bf(tile[c4 + 2][nn]);
    o.w = f2bf(tile[c4 + 3][nn]);
    *(u16x4*)(Wt + (size_t)(bn * 64 + nn) * K + bk * 64 + c4) = o;
  }
}

// ---------------------------------------------------------------------------
// Kernel 3: m201-faithful 256x256 8-phase bf16 GEMM (C = A * Bt^T), fp32 acc.
// 512 thr = 8 waves (2M x 4N); INTERLEAVED wave mapping: m-frag mi -> row
// (mi*2+wr)*16, n-frag nj -> col (nj*4+wc)*16, so MFMA quadrant mq/nq ==
// staging half (rows 0-127 / 128-255). LDS 128KB: A [buf][half] 4x16KB @0,
// B @65536. Octet XOR swizzle: phys_slot = oct ^ ((row>>1)&7) (full 32-bank
// spread), applied on GLOBAL stage source + ds_read addr (LDS dest linear).
// Per K-tile 4 phases, quadrant walk (m0,n0)(m0,n1)(m1,n1)(m1,n0), both B
// quads live (reads 12/4/8/0). Phase = [reads][stage][lgkm8?][bar][lgkm0]
// [setprio 16xMFMA][bar]. Stage map per iteration (Ta=2it buf0, Tb=2it+1
// buf1, Sa=Ta+2, Sb=Tb+2): P1:A(Tb)h1 P2:B(Sa)h0 P3:A(Sa)h0 P4:B(Sa)h1
// P5:A(Sa)h1 P6:B(Sb)h0 P7:A(Sb)h0 P8:B(Sb)h1. vmcnt(6) at P4/P8 only
// (ledger: retires exactly the 4 halves of the next-consumed tile, ages 3-6
// phases). Prologue: 7 half-stages + vmcnt(6).
// EPI 0: out_bf16 = gelu_tanh(C + eb1[n]);  EPI 1: out_f32 = C + eb1 + eb2
// + add1 + add2.
// ---------------------------------------------------------------------------
#define QMFMA(AQ, BQ, MILO, NJLO)                                           \
  __builtin_amdgcn_s_setprio(1);                                            \
  _Pragma("unroll") for (int i5 = 0; i5 < 4; ++i5)                          \
  _Pragma("unroll") for (int j5 = 0; j5 < 2; ++j5)                          \
  _Pragma("unroll") for (int k5 = 0; k5 < 2; ++k5)                          \
    acc[MILO + i5][NJLO + j5] = __builtin_amdgcn_mfma_f32_16x16x32_bf16(    \
        AQ[i5 * 2 + k5], BQ[j5 * 2 + k5], acc[MILO + i5][NJLO + j5], 0, 0, 0); \
  __builtin_amdgcn_s_setprio(0);

#define BAR __builtin_amdgcn_s_barrier()
#define LGKM0 do { asm volatile("s_waitcnt lgkmcnt(0)" ::: "memory"); SB0; } while (0)
#define LGKM8 do { asm volatile("s_waitcnt lgkmcnt(8)" ::: "memory"); } while (0)
#define VM6 do { SB0; asm volatile("s_waitcnt vmcnt(6)" ::: "memory"); SB0; } while (0)

template <int EPI>
__global__ __launch_bounds__(512, 2) void gemm8p_kernel(
    const bf16_t* __restrict__ A, const bf16_t* __restrict__ Bt,
    int M, int N, int K,
    const float* __restrict__ eb1, const float* __restrict__ eb2,
    const float* __restrict__ add1, const float* __restrict__ add2,
    bf16_t* __restrict__ outb, float* __restrict__ outf) {
  __shared__ char lds[131072];  // A: [buf][half] 4 x 16KB @0; B @65536

  const int t = threadIdx.x;
  const int l = t & 63;
  const int wid = t >> 6;
  const int wr = wid >> 2;  // 0..1
  const int wc = wid & 3;   // 0..3

  // Block -> tile: XCD chunk swizzle, 32-wg chunks shaped 8(tm) x 4(tn) (R5).
  int nwg = gridDim.x;
  int bid = blockIdx.x;
  int wg = (bid & 7) * (nwg >> 3) + (bid >> 3);
  int ntm = M >> 8;
  int chunk = wg >> 5, s5 = wg & 31;
  int cmn = ntm >> 3;
  int cm = chunk % cmn, cn = chunk / cmn;
  int tm = cm * 8 + (s5 & 7);
  int tn = cn * 4 + (s5 >> 3);
  size_t m0 = (size_t)tm * 256, n0 = (size_t)tn * 256;

  f32x4 acc[8][4];
#pragma unroll
  for (int i = 0; i < 8; ++i)
#pragma unroll
    for (int j = 0; j < 4; ++j) acc[i][j] = {0.f, 0.f, 0.f, 0.f};

  // ---- staging thread map: half-tile = [128 rows][64 k] = 1024 x 16B.
  // thread t -> chunks t (row t>>3, slot t&7) and t+512 (row +64, same slot).
  // LDS dest linear; GLOBAL source k-octet = slot ^ ((row>>1)&7).
  const int rh = t >> 3;
  const int sl = t & 7;
  const int oc = sl ^ ((rh >> 1) & 7);  // same for row rh+64 ((+64)>>1 keeps &7)
  const bf16_t* sA0 = A + (m0 + rh) * (size_t)K + oc * 8;
  const bf16_t* sA1 = A + (m0 + rh + 64) * (size_t)K + oc * 8;
  const bf16_t* sB0 = Bt + (n0 + rh) * (size_t)K + oc * 8;
  const bf16_t* sB1 = Bt + (n0 + rh + 64) * (size_t)K + oc * 8;

  auto stA = [&](int b, int h, int T) {
    GLDS16(sA0 + (size_t)h * 128 * K + (size_t)T * 64,
           lds + b * 32768 + h * 16384 + t * 16);
    GLDS16(sA1 + (size_t)h * 128 * K + (size_t)T * 64,
           lds + b * 32768 + h * 16384 + (t + 512) * 16);
  };
  auto stB = [&](int b, int h, int T) {
    GLDS16(sB0 + (size_t)h * 128 * K + (size_t)T * 64,
           lds + 65536 + b * 32768 + h * 16384 + t * 16);
    GLDS16(sB1 + (size_t)h * 128 * K + (size_t)T * 64,
           lds + 65536 + b * 32768 + h * 16384 + (t + 512) * 16);
  };

  // ---- fragment read offsets (within operand region; +buf*32768 at use).
  // A frag (mi,ks): global row (mi*2+wr)*16 + (l&15) -> half mi>>2,
  // row-in-half lr=(mi&3)*32+wr*16+(l&15); octet o=ks*4+(l>>4);
  // phys slot = o ^ ((lr>>1)&7)  -> full 32-bank spread per instruction.
  int offA[8][2], offB[4][2];
#pragma unroll
  for (int mi = 0; mi < 8; ++mi) {
    int h = mi >> 2;
    int lr = (mi & 3) * 32 + wr * 16 + (l & 15);
#pragma unroll
    for (int ks = 0; ks < 2; ++ks) {
      int o = ks * 4 + (l >> 4);
      offA[mi][ks] = h * 16384 + lr * 128 + ((o ^ ((lr >> 1) & 7)) << 4);
    }
  }
#pragma unroll
  for (int nj = 0; nj < 4; ++nj) {
    int h = nj >> 1;
    int lc = (nj & 1) * 64 + wc * 16 + (l & 15);
#pragma unroll
    for (int ks = 0; ks < 2; ++ks) {
      int o = ks * 4 + (l >> 4);
      offB[nj][ks] = 65536 + h * 16384 + lc * 128 + ((o ^ ((lc >> 1) & 7)) << 4);
    }
  }

  auto rd8 = [&](int off) -> bf16x8 {
    return *(const bf16x8*)(const void*)(lds + off);
  };

  const int NT = K >> 6;   // K-tiles of 64
  const int NI = NT >> 1;  // iterations (2 tiles each)

  // ---- prologue: tile0 (buf0, 4 halves) + tile1 (buf1, 3 halves) = 14 loads.
  // vmcnt(6) retires the 8 oldest = tile0 complete; tile1's 6 stay in flight.
  stB(0, 0, 0); stA(0, 0, 0); stB(0, 1, 0); stA(0, 1, 0);
  stB(1, 0, 1); stA(1, 0, 1); stB(1, 1, 1);
  SB0;
  asm volatile("s_waitcnt vmcnt(6)" ::: "memory");
  SB0;
  BAR;

  bf16x8 aQ[8], bQ0[4], bQ1[4];
  for (int it = 0; it < NI; ++it) {
    const int Tb = 2 * it + 1;
    int Sa = 2 * it + 2; if (Sa >= NT) Sa = NT - 1;  // tail: dead prefetch
    int Sb = 2 * it + 3; if (Sb >= NT) Sb = NT - 1;

    // ---------- tile Ta = 2it (buf0) ----------
    // P1: rd A-h0 quad + B-h0 quad (12); stage A(Tb)h1 -> buf1.
#pragma unroll
    for (int i = 0; i < 4; ++i)
#pragma unroll
      for (int ks = 0; ks < 2; ++ks) aQ[i * 2 + ks] = rd8(offA[i][ks]);
#pragma unroll
    for (int j = 0; j < 2; ++j)
#pragma unroll
      for (int ks = 0; ks < 2; ++ks) bQ0[j * 2 + ks] = rd8(offB[j][ks]);
    stA(1, 1, Tb);
    SB0; LGKM8; BAR; LGKM0;
    QMFMA(aQ, bQ0, 0, 0)
    BAR;
    // P2: rd B-h1 quad (4); stage B(Sa)h0 (old buf0.B.h0 last read P1).
#pragma unroll
    for (int j = 0; j < 2; ++j)
#pragma unroll
      for (int ks = 0; ks < 2; ++ks) bQ1[j * 2 + ks] = rd8(offB[2 + j][ks]);
    stB(0, 0, Sa);
    SB0; BAR; LGKM0;
    QMFMA(aQ, bQ1, 0, 2)
    BAR;
    // P3: rd A-h1 quad (8); stage A(Sa)h0 (old last read P1).
#pragma unroll
    for (int i = 0; i < 4; ++i)
#pragma unroll
      for (int ks = 0; ks < 2; ++ks) aQ[i * 2 + ks] = rd8(offA[4 + i][ks]);
    stA(0, 0, Sa);
    SB0; BAR; LGKM0;
    QMFMA(aQ, bQ1, 4, 2)
    BAR;
    // P4: no reads; stage B(Sa)h1 (old last read P2); vmcnt(6): retires
    // tile Tb's 4 halves (P6',P7',P8',P1 stages) before P5 reads buf1.
    stB(0, 1, Sa);
    VM6; BAR;
    QMFMA(aQ, bQ0, 4, 0)
    BAR;

    // ---------- tile Tb = 2it+1 (buf1) ----------
    // P5: rd A-h0 + B-h0 from buf1 (12); stage A(Sa)h1 (old last read P3).
#pragma unroll
    for (int i = 0; i < 4; ++i)
#pragma unroll
      for (int ks = 0; ks < 2; ++ks) aQ[i * 2 + ks] = rd8(32768 + offA[i][ks]);
#pragma unroll
    for (int j = 0; j < 2; ++j)
#pragma unroll
      for (int ks = 0; ks < 2; ++ks) bQ0[j * 2 + ks] = rd8(32768 + offB[j][ks]);
    stA(0, 1, Sa);
    SB0; LGKM8; BAR; LGKM0;
    QMFMA(aQ, bQ0, 0, 0)
    BAR;
    // P6: rd B-h1 (4); stage B(Sb)h0 (old buf1.B.h0 last read P5).
#pragma unroll
    for (int j = 0; j < 2; ++j)
#pragma unroll
      for (int ks = 0; ks < 2; ++ks)
        bQ1[j * 2 + ks] = rd8(32768 + offB[2 + j][ks]);
    stB(1, 0, Sb);
    SB0; BAR; LGKM0;
    QMFMA(aQ, bQ1, 0, 2)
    BAR;
    // P7: rd A-h1 (8); stage A(Sb)h0 (old last read P5).
#pragma unroll
    for (int i = 0; i < 4; ++i)
#pragma unroll
      for (int ks = 0; ks < 2; ++ks)
        aQ[i * 2 + ks] = rd8(32768 + offA[4 + i][ks]);
    stA(1, 0, Sb);
    SB0; BAR; LGKM0;
    QMFMA(aQ, bQ1, 4, 2)
    BAR;
    // P8: no reads; stage B(Sb)h1 (old last read P6); vmcnt(6): retires
    // tile Sa's 4 halves (P2,P3,P4,P5 stages) before next-P1 reads buf0.
    stB(1, 1, Sb);
    VM6; BAR;
    QMFMA(aQ, bQ0, 4, 0)
    BAR;
  }
  asm volatile("s_waitcnt vmcnt(0)" ::: "memory");

  // Epilogue. Interleaved mapping: row = m0 + (mi*2+wr)*16 + (l>>4)*4 + i2,
  // col = n0 + (nj*4+wc)*16 + (l&15).
  int lr4 = (l >> 4) * 4;
  int lc = l & 15;
#pragma unroll
  for (int mi = 0; mi < 8; ++mi) {
#pragma unroll
    for (int i2 = 0; i2 < 4; ++i2) {
      int rrow = (int)m0 + (mi * 2 + wr) * 16 + lr4 + i2;
      size_t base = (size_t)rrow * N;
#pragma unroll
      for (int nj = 0; nj < 4; ++nj) {
        int col = (int)n0 + (nj * 4 + wc) * 16 + lc;
        float v = acc[mi][nj][i2];
        if (EPI == 0) {
          float x = v + eb1[col];
          float u = 0.7978845608028654f * (x + 0.044715f * x * x * x);
          float th = 1.f - 2.f / (__expf(2.f * u) + 1.f);  // tanh(u)
          outb[base + col] = f2bf(0.5f * x * (1.f + th));
        } else {
          outf[base + col] =
              v + eb1[col] + eb2[col] + add1[base + col] + add2[base + col];
        }
      }
    }
  }
}

// ---------------------------------------------------------------------------
extern "C" void kernel_launch(void* const* d_in, const int* in_sizes, int n_in,
                              void* d_out, int out_size, void* d_ws,
                              size_t ws_size, hipStream_t stream) {
  const float* input = (const float*)d_in[0];
  const float* residual = (const float*)d_in[1];
  const float* bias = (const float*)d_in[3];
  const float* attn_nw = (const float*)d_in[4];
  const float* attn_nb = (const float*)d_in[5];
  const float* inter_w = (const float*)d_in[6];   // [H, DFF]
  const float* inter_b = (const float*)d_in[7];   // [DFF]
  const float* output_w = (const float*)d_in[8];  // [DFF, H]
  const float* output_b = (const float*)d_in[9];  // [H]
  float* out = (float*)d_out;

  char* ws = (char*)d_ws;
  bf16_t* lnb = (bf16_t*)ws;
  bf16_t* w1t = (bf16_t*)(ws + (size_t)NROWS * H_DIM * 2);
  bf16_t* w2t = (bf16_t*)(ws + (size_t)NROWS * H_DIM * 2 +
                          (size_t)H_DIM * DFF_DIM * 2);
  bf16_t* inter = (bf16_t*)(ws + (size_t)NROWS * H_DIM * 2 +
                            2 * (size_t)H_DIM * DFF_DIM * 2);

  fused_ln_kernel<<<NROWS, 256, 0, stream>>>(input, residual, bias, attn_nw,
                                             attn_nb, lnb);
  transpose_cvt_kernel<<<(H_DIM / 64) * (DFF_DIM / 64), 256, 0, stream>>>(
      inter_w, w1t, H_DIM, DFF_DIM);
  transpose_cvt_kernel<<<(DFF_DIM / 64) * (H_DIM / 64), 256, 0, stream>>>(
      output_w, w2t, DFF_DIM, H_DIM);
  gemm8p_kernel<0><<<(NROWS / 256) * (DFF_DIM / 256), 512, 0, stream>>>(
      lnb, w1t, NROWS, DFF_DIM, H_DIM, inter_b, nullptr, nullptr, nullptr,
      inter, nullptr);
  gemm8p_kernel<1><<<(NROWS / 256) * (H_DIM / 256), 512, 0, stream>>>(
      inter, w2t, NROWS, H_DIM, DFF_DIM, bias, output_b, residual, input,
      nullptr, out);
}